// Round 4
// baseline (222.839 us; speedup 1.0000x reference)
//
#include <hip/hip_runtime.h>
#include <stdint.h>

// DyDCNv2 + GroupNorm(16). B=8, C=O=256, H=W=64, fp32 in/out.
// Implicit GEMM M=32768,N=256,K=2304 bf16 MFMA.
// R11: producer/consumer wave specialization. R10 post-mortem: +16 regs at
// (512,4) blew the 128-reg unified cap -> 70MB scratch spill (WRITE 33->101MB).
// R8's real limit: all 8 waves lockstep through load->MFMA->interp->barrier,
// so pipe times SUM (~6.7k cy) instead of overlap; only 2 blocks/CU gave
// partial cross-phase cover. Fix: waves 0-3 = producers (gather+interp+LDS
// write, g2[2][8] carried, no acc), waves 4-7 = consumers (bf load + ds_read
// + 32 MFMA, acc 4x4 AGPR, no gathers). Phase overlap is structural: P and C
// run concurrently on each SIMD. Consumer vmcnt decoupled from gathers (per-
// wave counters). Reg union ~200 -> (512,2), 1 block/CU, grid 512 in 2 rounds.
// Occupancy counter WILL read ~25% -- by design. Per-CU-step VMEM halves.

#define B_ 8
#define C_ 256
#define O_ 256
#define H_ 64
#define W_ 64
#define HW_ 4096
#define KTOT 2304
#define GROUPS_ 16
#define EPS_ 1e-5f
#define NSTEP 36           // 36 steps x 64 ch (k-major: k = s>>2, c0 = (s&3)*64)
#define VROW 72            // lds_v row stride in u16 (64 data + 8 pad)

typedef float  f32x4  __attribute__((ext_vector_type(4)));
typedef short  short8 __attribute__((ext_vector_type(8)));
typedef unsigned int   u32;
typedef unsigned short u16;

// workspace layout (bytes)
#define XT_BYTES   (B_*HW_*C_*2)                // 16,777,216  xt [B][HW][C] bf16
#define WIMG_OFF   XT_BYTES
#define WIMG_BYTES (72*16*64*16)                // 1,179,648  frag-packed bf16 weights
#define STATS_OFF  (WIMG_OFF + WIMG_BYTES)      // 256 floats

__device__ __forceinline__ u32 bf16r(float f) {  // RNE f32->bf16
    u32 u = __float_as_uint(f);
    return (u + 0x7fffu + ((u >> 16) & 1u)) >> 16;
}
__device__ __forceinline__ u32 pack_bf16x2(float lo, float hi) {
    return bf16r(lo) | (bf16r(hi) << 16);
}
// 1-op pack: D = [hi.b3 hi.b2 lo.b3 lo.b2] (truncation round; errors cancel over K)
__device__ __forceinline__ u32 pack_perm(float lo, float hi) {
    return __builtin_amdgcn_perm(__float_as_uint(hi), __float_as_uint(lo), 0x07060302u);
}
__device__ __forceinline__ float bflo(u32 u) { return __uint_as_float(u << 16); }
// free: high bf16 in place; low 16 bits carry the sibling bf16 (rel err < 2^-8)
__device__ __forceinline__ float bfhi_f(u32 u) { return __uint_as_float(u); }

// barrier waiting only on LDS ops: register-destined global loads stay in flight
__device__ __forceinline__ void barrier_lds() {
    asm volatile("s_waitcnt lgkmcnt(0)\n\ts_barrier" ::: "memory");
}

// ---------------------------------------------------------------- prep: transpose + packw
__global__ void k_prep(const float* __restrict__ x, u16* __restrict__ xt,
                       const float* __restrict__ w, u16* __restrict__ wimg,
                       float* __restrict__ stats) {
    const int bid = blockIdx.x;
    const int tid = threadIdx.x;
    if (bid >= 2048 + 288) {           // last block: zero GN stats (replaces memset)
        stats[tid] = 0.f;
        return;
    }
    if (bid < 2048) {
        // transpose x[B][C][HW] -> xt[B][HW][C] bf16, 64c x 64p tiles
        __shared__ float tile[64][65];
        const int b = bid >> 8, ct = (bid >> 6) & 3, pt = bid & 63;
#pragma unroll
        for (int pass = 0; pass < 4; ++pass) {
            const int r  = (tid >> 4) + pass * 16;
            const int pq = tid & 15;
            const f32x4 v = *(const f32x4*)&x[(((size_t)(b * C_ + ct * 64 + r)) << 12)
                                              + pt * 64 + pq * 4];
            tile[r][pq * 4 + 0] = v.x;
            tile[r][pq * 4 + 1] = v.y;
            tile[r][pq * 4 + 2] = v.z;
            tile[r][pq * 4 + 3] = v.w;
        }
        __syncthreads();
        const int pr = tid >> 2, cg = tid & 3;    // 64 p-rows x 4 groups of 16 ch
        u32 o[8];
#pragma unroll
        for (int j = 0; j < 8; ++j)
            o[j] = pack_bf16x2(tile[cg * 16 + 2 * j][pr], tile[cg * 16 + 2 * j + 1][pr]);
        u16* dst = &xt[(((size_t)b << 12) + pt * 64 + pr) * 256 + ct * 64 + cg * 16];
        *(uint4*)dst       = *(uint4*)&o[0];
        *(uint4*)(dst + 8) = *(uint4*)&o[4];
    } else {
        // pack weights: 1 item/thread over 288 blocks (no serial tail).
        // wimg[sub][frag][lane][8], sub=k*8+ctile; lane(col,quad) holds
        // W[n=frag*16+col][c0+quad*8+j][k]
        const int item = (bid - 2048) * 256 + tid;    // 0..73727
        if (item < 72 * 1024) {
            const int sub = item >> 10;
            const int idx = item & 1023;              // frag*64 + lane
            const int k  = sub >> 3;
            const int c0 = (sub & 7) * 32;
            const int lane = idx & 63;
            const int frag = idx >> 6;
            const int col = lane & 15, quad = lane >> 4;
            const int n = frag * 16 + col;
            const float* src = w + (size_t)n * KTOT + (size_t)(c0 + quad * 8) * 9 + k;
            u32 o[4];
#pragma unroll
            for (int j = 0; j < 4; ++j)
                o[j] = pack_bf16x2(src[(size_t)(2 * j) * 9], src[(size_t)(2 * j + 1) * 9]);
            *(uint4*)&wimg[((size_t)sub * 1024 + idx) * 8] = *(uint4*)o;
        }
    }
}

// ---------------------------------------------------------------- k_dcn helpers
// producer role: thread = (ppos 0..63, pslot 0..3); 16 channels (32 B) per corner.
__device__ __forceinline__ void issue_gather16(const u16* __restrict__ cb,
                                               const float* __restrict__ mwp,
                                               const int* __restrict__ mip,
                                               int ppos, uint4 g[8], f32x4& mw) {
    mw = *(const f32x4*)&mwp[ppos * 4];
    const int4 ix = *(const int4*)&mip[ppos * 4];
    const u16* p0 = cb + ix.x;
    const u16* p1 = cb + ix.y;
    const u16* p2 = cb + ix.z;
    const u16* p3 = cb + ix.w;
    g[0] = *(const uint4*)p0; g[1] = *(const uint4*)(p0 + 8);
    g[2] = *(const uint4*)p1; g[3] = *(const uint4*)(p1 + 8);
    g[4] = *(const uint4*)p2; g[5] = *(const uint4*)(p2 + 8);
    g[6] = *(const uint4*)p3; g[7] = *(const uint4*)(p3 + 8);
}

__device__ __forceinline__ void interp_store16(const uint4 g[8], f32x4 mw, u16* dst) {
    float s[16];
#pragma unroll
    for (int i = 0; i < 16; ++i) s[i] = 0.f;
    const float ww[4] = {mw.x, mw.y, mw.z, mw.w};
#pragma unroll
    for (int cr = 0; cr < 4; ++cr) {
        const float wg = ww[cr];
        const uint4 a = g[2 * cr], bq = g[2 * cr + 1];
        s[0]  += wg * bflo(a.x);  s[1]  += wg * bfhi_f(a.x);
        s[2]  += wg * bflo(a.y);  s[3]  += wg * bfhi_f(a.y);
        s[4]  += wg * bflo(a.z);  s[5]  += wg * bfhi_f(a.z);
        s[6]  += wg * bflo(a.w);  s[7]  += wg * bfhi_f(a.w);
        s[8]  += wg * bflo(bq.x); s[9]  += wg * bfhi_f(bq.x);
        s[10] += wg * bflo(bq.y); s[11] += wg * bfhi_f(bq.y);
        s[12] += wg * bflo(bq.z); s[13] += wg * bfhi_f(bq.z);
        s[14] += wg * bflo(bq.w); s[15] += wg * bfhi_f(bq.w);
    }
    uint4 pk0, pk1;
    pk0.x = pack_perm(s[0], s[1]);   pk0.y = pack_perm(s[2], s[3]);
    pk0.z = pack_perm(s[4], s[5]);   pk0.w = pack_perm(s[6], s[7]);
    pk1.x = pack_perm(s[8], s[9]);   pk1.y = pack_perm(s[10], s[11]);
    pk1.z = pack_perm(s[12], s[13]); pk1.w = pack_perm(s[14], s[15]);
    *(uint4*)dst = pk0;
    *(uint4*)(dst + 8) = pk1;
}

// ---------------------------------------------------------------- main fused DCN GEMM
// grid 512: b = gid%8 (XCD-affine), m-tile 64 pos. 512 thr = 8 waves.
// Waves 0-3 PRODUCERS: (ppos,pslot16) gather 4 corners + bilinear interp ->
//   LDS A-tile (dbuf). Carried: g2[2][8] (distance-2 prefetch) + mw2.
// Waves 4-7 CONSUMERS: wave cw covers 64 pos x n in [cw*64,+64): bf 8 frags,
//   af 8 ds_read_b128, 32 MFMA/step into acc[4][4].
// (512,2): cap 256 regs, 1 block/CU, grid runs in 2 rounds.
__launch_bounds__(512, 2)
__global__ void k_dcn(const u16* __restrict__ xt, const u16* __restrict__ wimg,
                      const float* __restrict__ offp, const float* __restrict__ mskp,
                      float* __restrict__ out, float* __restrict__ stats) {
    __shared__ __align__(16) float meta_w[9 * 64 * 4];   // 9216 B
    __shared__ __align__(16) int   meta_i[9 * 64 * 4];   // 9216 B
    __shared__ __align__(16) u16   lds_v[2][64 * VROW];  // 18432 B dbuf A tile

    const int tid = threadIdx.x;
    const int gid = blockIdx.x;
    const int b   = gid & 7;            // XCD-affine
    const int m0  = (gid >> 3) * 64;
    const int lane = tid & 63, wid = tid >> 6;
    const bool producer = (wid < 4);

    const u16* xtb = xt + ((size_t)b << 20);

    // ---- bilinear meta for 64 positions x 9 kernel points, once (all waves)
    for (int it = tid; it < 576; it += 512) {
        const int pos = it & 63, k = it >> 6;
        const int pg = m0 + pos;
        const int hh = pg >> 6, wwi = pg & 63;
        const float dy = offp[((size_t)(b * 18 + 2 * k) << 12) + pg];
        const float dx = offp[((size_t)(b * 18 + 2 * k + 1) << 12) + pg];
        const float mv = mskp[((size_t)(b * 9 + k) << 12) + pg];
        const float ys = (float)(hh + (k / 3) - 1) + dy;
        const float xs = (float)(wwi + (k % 3) - 1) + dx;
        const float y0f = floorf(ys), x0f = floorf(xs);
        const int y0 = (int)y0f, x0 = (int)x0f;
        const float wy1 = ys - y0f, wx1 = xs - x0f;
        const float wy0 = 1.f - wy1, wx0 = 1.f - wx1;
        const int y1 = y0 + 1, x1 = x0 + 1;
        const float vy0 = (y0 >= 0 && y0 < H_) ? 1.f : 0.f;
        const float vy1 = (y1 >= 0 && y1 < H_) ? 1.f : 0.f;
        const float vx0 = (x0 >= 0 && x0 < W_) ? 1.f : 0.f;
        const float vx1 = (x1 >= 0 && x1 < W_) ? 1.f : 0.f;
        const int y0c = min(max(y0, 0), H_ - 1), y1c = min(max(y1, 0), H_ - 1);
        const int x0c = min(max(x0, 0), W_ - 1), x1c = min(max(x1, 0), W_ - 1);
        meta_w[it * 4 + 0] = mv * wy0 * wx0 * vy0 * vx0;
        meta_w[it * 4 + 1] = mv * wy0 * wx1 * vy0 * vx1;
        meta_w[it * 4 + 2] = mv * wy1 * wx0 * vy1 * vx0;
        meta_w[it * 4 + 3] = mv * wy1 * wx1 * vy1 * vx1;
        meta_i[it * 4 + 0] = (y0c * W_ + x0c) << 8;   // row offsets in u16 units
        meta_i[it * 4 + 1] = (y0c * W_ + x1c) << 8;
        meta_i[it * 4 + 2] = (y1c * W_ + x0c) << 8;
        meta_i[it * 4 + 3] = (y1c * W_ + x1c) << 8;
    }
    __syncthreads();

    // ---- role-local state
    // producer: thread = (ppos 0..63, pslot 0..3 of 16 ch)
    const int ppos = tid >> 2, pslot = tid & 3;
    const u16* gb = xtb + pslot * 16;
    u16* wdst0 = &lds_v[0][ppos * VROW + pslot * 16];
    u16* wdst1 = &lds_v[1][ppos * VROW + pslot * 16];
    uint4 g2[2][8]; f32x4 mw2[2];
    // consumer: wave cw covers n in [cw*64, +64)
    const int cw = wid - 4;
    const int col = lane & 15, quad = lane >> 4;
    f32x4 acc[4][4];

    if (producer) {
        // prologue: stage step 0 into buf0; leave g(1) in flight (set 1)
        issue_gather16(gb, &meta_w[0], &meta_i[0], ppos, g2[0], mw2[0]);       // s=0
        interp_store16(g2[0], mw2[0], wdst0);
        issue_gather16(gb + 64, &meta_w[0], &meta_i[0], ppos, g2[1], mw2[1]);  // s=1
    } else {
#pragma unroll
        for (int i = 0; i < 4; ++i)
#pragma unroll
            for (int j = 0; j < 4; ++j) acc[i][j] = (f32x4){0.f, 0.f, 0.f, 0.f};
    }
    __syncthreads();

#pragma unroll 2
    for (int s = 0; s < NSTEP; ++s) {
        if (producer) {
            // issue gathers for s+2 into set s&1 (its g(s) was consumed at s-1);
            // interp(s+1) below waits vmcnt<=8, so these stay in flight ~1 step
            if (s + 2 < NSTEP) {
                const int sn = s + 2;
                issue_gather16(gb + (sn & 3) * 64,
                               &meta_w[(sn >> 2) * 256], &meta_i[(sn >> 2) * 256],
                               ppos, g2[s & 1], mw2[s & 1]);
            }
            // interp s+1 (gathers issued at s-1) into buf (s+1)&1
            if (s + 1 < NSTEP)
                interp_store16(g2[(s + 1) & 1], mw2[(s + 1) & 1],
                               ((s + 1) & 1) ? wdst1 : wdst0);
        } else {
            // B frags for this step (consumer vmcnt tracks ONLY these)
            short8 bf[8];
#pragma unroll
            for (int kc = 0; kc < 2; ++kc)
#pragma unroll
                for (int ni = 0; ni < 4; ++ni)
                    bf[kc * 4 + ni] = *(const short8*)
                        &wimg[(((size_t)(2 * s + kc) * 16 + cw * 4 + ni) * 64 + lane) * 8];
            // A frags + MFMA from buf s&1
#pragma unroll
            for (int kc = 0; kc < 2; ++kc) {
                short8 af[4];
#pragma unroll
                for (int mi = 0; mi < 4; ++mi)
                    af[mi] = *(const short8*)
                        &lds_v[s & 1][(mi * 16 + col) * VROW + kc * 32 + quad * 8];
#pragma unroll
                for (int mi = 0; mi < 4; ++mi)
#pragma unroll
                    for (int ni = 0; ni < 4; ++ni)
                        acc[mi][ni] = __builtin_amdgcn_mfma_f32_16x16x32_bf16(
                            af[mi], bf[kc * 4 + ni], acc[mi][ni], 0, 0, 0);
            }
        }
        // uniform LDS-only barrier: producer's register gathers stay in flight
        if (s + 1 < NSTEP) barrier_lds();
    }

    if (producer) return;

    // ---- epilogue (consumers): D row(pos)=quad*4+r, col(o)=lane&15.
#pragma unroll
    for (int mi = 0; mi < 4; ++mi)
#pragma unroll
        for (int ni = 0; ni < 4; ++ni) {
            const int o  = cw * 64 + ni * 16 + col;
            const int pg = m0 + mi * 16 + quad * 4;
            *(f32x4*)(out + (((size_t)b * O_ + o) << 12) + pg) = acc[mi][ni];
        }

    // ---- GN stats: (cw, ni) = one 16-channel group x 64 positions
#pragma unroll
    for (int ni = 0; ni < 4; ++ni) {
        float s1 = 0.f, s2 = 0.f;
#pragma unroll
        for (int mi = 0; mi < 4; ++mi) {
            f32x4 v = acc[mi][ni];
            s1 += v.x + v.y + v.z + v.w;
            s2 += v.x * v.x + v.y * v.y + v.z * v.z + v.w * v.w;
        }
#pragma unroll
        for (int d = 32; d > 0; d >>= 1) {
            s1 += __shfl_xor(s1, d, 64);
            s2 += __shfl_xor(s2, d, 64);
        }
        if (lane == 0) {
            const int gI = cw * 4 + ni;
            atomicAdd(&stats[b * GROUPS_ + gI], s1);
            atomicAdd(&stats[128 + b * GROUPS_ + gI], s2);
        }
    }
}

// ---------------------------------------------------------------- apply GN in place
__global__ void k_gn(float* __restrict__ out, const float* __restrict__ stats,
                     const float* __restrict__ gamma, const float* __restrict__ beta) {
    const int blk = blockIdx.x;            // b*256 + o
    const int b = blk >> 8, o = blk & 255;
    const int gI = b * GROUPS_ + (o >> 4);
    const float n = 65536.f;               // (C/G)*H*W
    const float mean = stats[gI] / n;
    const float var  = stats[128 + gI] / n - mean * mean;
    const float inv  = rsqrtf(fmaxf(var, 0.f) + EPS_);
    const float scale = inv * gamma[o];
    const float shift = beta[o] - mean * scale;
    f32x4* p = (f32x4*)(out + ((size_t)blk << 12));
    const int t = threadIdx.x;
#pragma unroll
    for (int i = 0; i < 4; ++i) {
        f32x4 v = p[t + i * 256];
        p[t + i * 256] = v * scale + shift;
    }
}

extern "C" void kernel_launch(void* const* d_in, const int* in_sizes, int n_in,
                              void* d_out, int out_size, void* d_ws, size_t ws_size,
                              hipStream_t stream) {
    const float* x     = (const float*)d_in[0];
    const float* offp  = (const float*)d_in[1];
    const float* mskp  = (const float*)d_in[2];
    const float* w     = (const float*)d_in[3];
    const float* gamma = (const float*)d_in[4];
    const float* beta  = (const float*)d_in[5];
    float* outp = (float*)d_out;

    u16*   xt    = (u16*)d_ws;
    u16*   wimg  = (u16*)((char*)d_ws + WIMG_OFF);
    float* stats = (float*)((char*)d_ws + STATS_OFF);

    k_prep<<<dim3(2048 + 288 + 1), dim3(256), 0, stream>>>(x, xt, w, wimg, stats);
    k_dcn<<<dim3(512), dim3(512), 0, stream>>>(xt, wimg, offp, mskp, outp, stats);
    k_gn<<<dim3(2048), dim3(256), 0, stream>>>(outp, stats, gamma, beta);
}

// Round 5
// 188.647 us; speedup vs baseline: 1.1812x; 1.1812x over previous
//
#include <hip/hip_runtime.h>
#include <stdint.h>

// DyDCNv2 + GroupNorm(16). B=8, C=O=256, H=W=64, fp32 in/out.
// Implicit GEMM M=32768,N=256,K=2304 bf16 MFMA.
// R12: BM=128 + async LDS weight staging. R8 (82.9us) analysis: no pipe >35%;
// dominant stall = synchronized post-barrier L2 bursts (64KB weights + 32KB
// gathers per CU-step demanded by all waves at once) + weight L2 traffic
// 512 blocks x 1.15MB = 590MB. R10 proved weights can't be register-dbuf'd
// (128-reg cap -> spill); R11 proved P/C wave split starves MFMA. Fix: one
// 1024-thr block/CU (16 waves, 4/SIMD like R8), tile 128pos x 256n:
// (1) weights via global_load_lds width-16, dbuf in LDS, issued 1 step ahead
//     -> halves weight L2 traffic (256 M-tiles), zero VGPR cost, latency
//     hidden by DMA. bf = ds_read_b128 at use.
// (2) A-tile/gather/interp = R8's proven pattern (VROW=72, 8ch-slot role,
//     distance-2 gather sets in regs).
// (3) counted vmcnt: DMA older than the step's 4 gathers -> pinned
//     s_waitcnt vmcnt(4) before lgkm-only barrier drains DMA, keeps gathers
//     flying (never vmcnt(0) mid-loop). sched_barrier(0) pins the count.
// LDS 127KB: wlds 64K + lds_v 36.9K + meta_w 18.4K + meta_i(u16) 9.2K.

#define B_ 8
#define C_ 256
#define O_ 256
#define H_ 64
#define W_ 64
#define HW_ 4096
#define KTOT 2304
#define GROUPS_ 16
#define EPS_ 1e-5f
#define NSTEP 36           // 36 steps x 64 ch (k-major: k = s>>2, c0 = (s&3)*64)
#define VROW 72            // lds_v row stride in u16 (64 data + 8 pad)
#define BM 128             // positions per block

typedef float  f32x4  __attribute__((ext_vector_type(4)));
typedef short  short8 __attribute__((ext_vector_type(8)));
typedef unsigned int   u32;
typedef unsigned short u16;

// workspace layout (bytes)
#define XT_BYTES   (B_*HW_*C_*2)                // 16,777,216  xt [B][HW][C] bf16
#define WIMG_OFF   XT_BYTES
#define WIMG_BYTES (72*16*64*16)                // 1,179,648  frag-packed bf16 weights
#define STATS_OFF  (WIMG_OFF + WIMG_BYTES)      // 256 floats

__device__ __forceinline__ u32 bf16r(float f) {  // RNE f32->bf16
    u32 u = __float_as_uint(f);
    return (u + 0x7fffu + ((u >> 16) & 1u)) >> 16;
}
__device__ __forceinline__ u32 pack_bf16x2(float lo, float hi) {
    return bf16r(lo) | (bf16r(hi) << 16);
}
// 1-op pack: D = [hi.b3 hi.b2 lo.b3 lo.b2] (truncation round; errors cancel over K)
__device__ __forceinline__ u32 pack_perm(float lo, float hi) {
    return __builtin_amdgcn_perm(__float_as_uint(hi), __float_as_uint(lo), 0x07060302u);
}
__device__ __forceinline__ float bflo(u32 u) { return __uint_as_float(u << 16); }
// free: high bf16 in place; low 16 bits carry the sibling bf16 (rel err < 2^-8)
__device__ __forceinline__ float bfhi_f(u32 u) { return __uint_as_float(u); }

// barrier waiting only on LDS ops: register-destined global loads + DMA stay in flight
__device__ __forceinline__ void barrier_lds() {
    asm volatile("s_waitcnt lgkmcnt(0)\n\ts_barrier" ::: "memory");
}

// ---------------------------------------------------------------- prep: transpose + packw
__global__ void k_prep(const float* __restrict__ x, u16* __restrict__ xt,
                       const float* __restrict__ w, u16* __restrict__ wimg,
                       float* __restrict__ stats) {
    const int bid = blockIdx.x;
    const int tid = threadIdx.x;
    if (bid >= 2048 + 288) {           // last block: zero GN stats (replaces memset)
        stats[tid] = 0.f;
        return;
    }
    if (bid < 2048) {
        // transpose x[B][C][HW] -> xt[B][HW][C] bf16, 64c x 64p tiles
        __shared__ float tile[64][65];
        const int b = bid >> 8, ct = (bid >> 6) & 3, pt = bid & 63;
#pragma unroll
        for (int pass = 0; pass < 4; ++pass) {
            const int r  = (tid >> 4) + pass * 16;
            const int pq = tid & 15;
            const f32x4 v = *(const f32x4*)&x[(((size_t)(b * C_ + ct * 64 + r)) << 12)
                                              + pt * 64 + pq * 4];
            tile[r][pq * 4 + 0] = v.x;
            tile[r][pq * 4 + 1] = v.y;
            tile[r][pq * 4 + 2] = v.z;
            tile[r][pq * 4 + 3] = v.w;
        }
        __syncthreads();
        const int pr = tid >> 2, cg = tid & 3;    // 64 p-rows x 4 groups of 16 ch
        u32 o[8];
#pragma unroll
        for (int j = 0; j < 8; ++j)
            o[j] = pack_bf16x2(tile[cg * 16 + 2 * j][pr], tile[cg * 16 + 2 * j + 1][pr]);
        u16* dst = &xt[(((size_t)b << 12) + pt * 64 + pr) * 256 + ct * 64 + cg * 16];
        *(uint4*)dst       = *(uint4*)&o[0];
        *(uint4*)(dst + 8) = *(uint4*)&o[4];
    } else {
        // pack weights: 1 item/thread over 288 blocks (no serial tail).
        // wimg[sub][frag][lane][8], sub=k*8+ctile; lane(col,quad) holds
        // W[n=frag*16+col][c0+quad*8+j][k]
        const int item = (bid - 2048) * 256 + tid;    // 0..73727
        if (item < 72 * 1024) {
            const int sub = item >> 10;
            const int idx = item & 1023;              // frag*64 + lane
            const int k  = sub >> 3;
            const int c0 = (sub & 7) * 32;
            const int lane = idx & 63;
            const int frag = idx >> 6;
            const int col = lane & 15, quad = lane >> 4;
            const int n = frag * 16 + col;
            const float* src = w + (size_t)n * KTOT + (size_t)(c0 + quad * 8) * 9 + k;
            u32 o[4];
#pragma unroll
            for (int j = 0; j < 4; ++j)
                o[j] = pack_bf16x2(src[(size_t)(2 * j) * 9], src[(size_t)(2 * j + 1) * 9]);
            *(uint4*)&wimg[((size_t)sub * 1024 + idx) * 8] = *(uint4*)o;
        }
    }
}

// ---------------------------------------------------------------- k_dcn helpers
// gather role: thread = (gpos 0..127, slot 0..7); 8 channels (16 B) per corner.
__device__ __forceinline__ void issue_gather(const u16* __restrict__ cb,
                                             const float* __restrict__ mwp,
                                             const u16* __restrict__ mip,
                                             int gpos, uint4 g[4], f32x4& mw) {
    mw = *(const f32x4*)&mwp[gpos * 4];
    const ushort4 ix = *(const ushort4*)&mip[gpos * 4];
    g[0] = *(const uint4*)(cb + ((int)ix.x << 8));
    g[1] = *(const uint4*)(cb + ((int)ix.y << 8));
    g[2] = *(const uint4*)(cb + ((int)ix.z << 8));
    g[3] = *(const uint4*)(cb + ((int)ix.w << 8));
}

__device__ __forceinline__ void interp_store(const uint4 g[4], f32x4 mw, u16* dst) {
    float s[8];
#pragma unroll
    for (int i = 0; i < 8; ++i) s[i] = 0.f;
    const float ww[4] = {mw.x, mw.y, mw.z, mw.w};
#pragma unroll
    for (int cr = 0; cr < 4; ++cr) {
        const float wg = ww[cr];
        const uint4 a = g[cr];
        s[0] += wg * bflo(a.x);  s[1] += wg * bfhi_f(a.x);
        s[2] += wg * bflo(a.y);  s[3] += wg * bfhi_f(a.y);
        s[4] += wg * bflo(a.z);  s[5] += wg * bfhi_f(a.z);
        s[6] += wg * bflo(a.w);  s[7] += wg * bfhi_f(a.w);
    }
    uint4 pk;
    pk.x = pack_perm(s[0], s[1]);
    pk.y = pack_perm(s[2], s[3]);
    pk.z = pack_perm(s[4], s[5]);
    pk.w = pack_perm(s[6], s[7]);
    *(uint4*)dst = pk;
}

// DMA one step's weights (32KB, subs {2s,2s+1}) global -> LDS. 16 waves x 2
// chunks of 1KB each; LDS dest wave-uniform, global src per-lane. 2 instr/thread.
__device__ __forceinline__ void dma_weights(const u16* __restrict__ wimg, int s,
                                            u16* wlds_buf, int wid, int lane) {
    const u16* gsrc = wimg + (size_t)(2 * s) * 8192;   // 32KB contiguous
#pragma unroll
    for (int j = 0; j < 2; ++j) {
        const int chunk = j * 16 + wid;
        __builtin_amdgcn_global_load_lds((const u32*)(gsrc + chunk * 512 + lane * 8),
                                         (u32*)(wlds_buf + chunk * 512), 16, 0, 0);
    }
}

// ---------------------------------------------------------------- main fused DCN GEMM
// grid 256: b = gid&7 (XCD-affine), m-tile 128 pos. 1024 thr = 16 waves
// (mh = wid>>3, nw = wid&7): wave = 64 pos (m-half mh) x 32 n.
// (1024,4): 4 waves/SIMD, 1 block/CU, cap 128 regs.
__launch_bounds__(1024, 4)
__global__ void k_dcn(const u16* __restrict__ xt, const u16* __restrict__ wimg,
                      const float* __restrict__ offp, const float* __restrict__ mskp,
                      float* __restrict__ out, float* __restrict__ stats) {
    __shared__ __align__(16) float meta_w[9 * BM * 4];    // 18432 B
    __shared__ __align__(16) u16   meta_i[9 * BM * 4];    //  9216 B (row idx, <<8 at use)
    __shared__ __align__(16) u16   lds_v[2][BM * VROW];   // 36864 B dbuf A tile
    __shared__ __align__(16) u16   wlds[2][16384];        // 65536 B dbuf weights

    const int tid = threadIdx.x;
    const int gid = blockIdx.x;
    const int b   = gid & 7;            // XCD-affine (xt slice + wimg L2-resident)
    const int m0  = (gid >> 3) * BM;
    const int lane = tid & 63, wid = tid >> 6;
    const int mh = wid >> 3, nw = wid & 7;
    const int col = lane & 15, quad = lane >> 4;
    const int gpos = tid >> 3, slot = tid & 7;   // gather role: (pos 0..127, 8-ch slot)

    const u16* xtb = xt + ((size_t)b << 20);

    // ---- bilinear meta for 128 positions x 9 kernel points, once
    for (int it = tid; it < 9 * BM; it += 1024) {
        const int pos = it & (BM - 1), k = it >> 7;
        const int pg = m0 + pos;
        const int hh = pg >> 6, wwi = pg & 63;
        const float dy = offp[((size_t)(b * 18 + 2 * k) << 12) + pg];
        const float dx = offp[((size_t)(b * 18 + 2 * k + 1) << 12) + pg];
        const float mv = mskp[((size_t)(b * 9 + k) << 12) + pg];
        const float ys = (float)(hh + (k / 3) - 1) + dy;
        const float xs = (float)(wwi + (k % 3) - 1) + dx;
        const float y0f = floorf(ys), x0f = floorf(xs);
        const int y0 = (int)y0f, x0 = (int)x0f;
        const float wy1 = ys - y0f, wx1 = xs - x0f;
        const float wy0 = 1.f - wy1, wx0 = 1.f - wx1;
        const int y1 = y0 + 1, x1 = x0 + 1;
        const float vy0 = (y0 >= 0 && y0 < H_) ? 1.f : 0.f;
        const float vy1 = (y1 >= 0 && y1 < H_) ? 1.f : 0.f;
        const float vx0 = (x0 >= 0 && x0 < W_) ? 1.f : 0.f;
        const float vx1 = (x1 >= 0 && x1 < W_) ? 1.f : 0.f;
        const int y0c = min(max(y0, 0), H_ - 1), y1c = min(max(y1, 0), H_ - 1);
        const int x0c = min(max(x0, 0), W_ - 1), x1c = min(max(x1, 0), W_ - 1);
        meta_w[it * 4 + 0] = mv * wy0 * wx0 * vy0 * vx0;
        meta_w[it * 4 + 1] = mv * wy0 * wx1 * vy0 * vx1;
        meta_w[it * 4 + 2] = mv * wy1 * wx0 * vy1 * vx0;
        meta_w[it * 4 + 3] = mv * wy1 * wx1 * vy1 * vx1;
        meta_i[it * 4 + 0] = (u16)(y0c * W_ + x0c);   // row idx; <<8 (u16 units) at use
        meta_i[it * 4 + 1] = (u16)(y0c * W_ + x1c);
        meta_i[it * 4 + 2] = (u16)(y1c * W_ + x0c);
        meta_i[it * 4 + 3] = (u16)(y1c * W_ + x1c);
    }
    __syncthreads();

    // ---- prologue: DMAw(0); gathers(0)->g2[0], gathers(1)->g2[1]; interp(0).
    // interp(0)'s implicit wait (4 newer gathers) drains DMAw(0); explicit
    // vmcnt(4) re-asserts it, leaving only gathers(1) in flight.
    uint4 g2[2][4]; f32x4 mw2[2];
    dma_weights(wimg, 0, &wlds[0][0], wid, lane);
    issue_gather(xtb + 0 + slot * 8, &meta_w[0], &meta_i[0], gpos, g2[0], mw2[0]);
    issue_gather(xtb + 64 + slot * 8, &meta_w[0], &meta_i[0], gpos, g2[1], mw2[1]);
    interp_store(g2[0], mw2[0], &lds_v[0][gpos * VROW + slot * 8]);
    __builtin_amdgcn_sched_barrier(0);
    asm volatile("s_waitcnt vmcnt(4)" ::: "memory");
    __builtin_amdgcn_sched_barrier(0);
    __syncthreads();

    f32x4 acc[4][2];
#pragma unroll
    for (int i = 0; i < 4; ++i)
#pragma unroll
        for (int j = 0; j < 2; ++j) acc[i][j] = (f32x4){0.f, 0.f, 0.f, 0.f};

#pragma unroll 2
    for (int s = 0; s < NSTEP; ++s) {
        const int p = s & 1;

        // A. DMA weights for s+1 into the buffer freed at s-1
        if (s + 1 < NSTEP)
            dma_weights(wimg, s + 1, &wlds[1 - p][0], wid, lane);

        // B. gathers for s+2 into set freed by interp at s-1
        if (s + 2 < NSTEP) {
            const int sn = s + 2;
            issue_gather(xtb + (sn & 3) * 64 + slot * 8,
                         &meta_w[(sn >> 2) * (BM * 4)], &meta_i[(sn >> 2) * (BM * 4)],
                         gpos, g2[p], mw2[p]);
        }

        // C-E. bf from LDS (DMA'd at s-1), af from LDS, 16 MFMA
#pragma unroll
        for (int kc = 0; kc < 2; ++kc) {
            short8 bf[2];
#pragma unroll
            for (int ni = 0; ni < 2; ++ni)
                bf[ni] = *(const short8*)
                    &wlds[p][kc * 8192 + (nw * 2 + ni) * 512 + lane * 8];
            short8 af[4];
#pragma unroll
            for (int mi = 0; mi < 4; ++mi)
                af[mi] = *(const short8*)
                    &lds_v[p][(mh * 64 + mi * 16 + col) * VROW + kc * 32 + quad * 8];
#pragma unroll
            for (int mi = 0; mi < 4; ++mi)
#pragma unroll
                for (int ni = 0; ni < 2; ++ni)
                    acc[mi][ni] = __builtin_amdgcn_mfma_f32_16x16x32_bf16(
                        af[mi], bf[ni], acc[mi][ni], 0, 0, 0);
        }

        // F. interp s+1 (gathers issued at s-1; implicit wait leaves the 6
        //    newer ops -- DMAw(s+1) + gathers(s+2) -- in flight)
        if (s + 1 < NSTEP)
            interp_store(g2[1 - p], mw2[1 - p], &lds_v[1 - p][gpos * VROW + slot * 8]);

        // G. counted-vmcnt DMA drain + LDS-only barrier (gathers keep flying)
        if (s + 1 < NSTEP) {
            __builtin_amdgcn_sched_barrier(0);
            if (s + 2 < NSTEP) asm volatile("s_waitcnt vmcnt(4)" ::: "memory");
            else               asm volatile("s_waitcnt vmcnt(0)" ::: "memory");
            __builtin_amdgcn_sched_barrier(0);
            barrier_lds();
        }
    }

    // ---- epilogue: store pre-GN output. D: row(pos)=quad*4+r, col(o)=lane&15.
#pragma unroll
    for (int mi = 0; mi < 4; ++mi)
#pragma unroll
        for (int ni = 0; ni < 2; ++ni) {
            const int o  = nw * 32 + ni * 16 + col;
            const int pg = m0 + mh * 64 + mi * 16 + quad * 4;
            *(f32x4*)(out + (((size_t)b * O_ + o) << 12) + pg) = acc[mi][ni];
        }

    // ---- GN stats: (nw, ni) = one 16-channel group x 64 positions
#pragma unroll
    for (int ni = 0; ni < 2; ++ni) {
        float s1 = 0.f, s2 = 0.f;
#pragma unroll
        for (int mi = 0; mi < 4; ++mi) {
            f32x4 v = acc[mi][ni];
            s1 += v.x + v.y + v.z + v.w;
            s2 += v.x * v.x + v.y * v.y + v.z * v.z + v.w * v.w;
        }
#pragma unroll
        for (int d = 32; d > 0; d >>= 1) {
            s1 += __shfl_xor(s1, d, 64);
            s2 += __shfl_xor(s2, d, 64);
        }
        if (lane == 0) {
            const int gI = nw * 2 + ni;
            atomicAdd(&stats[b * GROUPS_ + gI], s1);
            atomicAdd(&stats[128 + b * GROUPS_ + gI], s2);
        }
    }
}

// ---------------------------------------------------------------- apply GN in place
__global__ void k_gn(float* __restrict__ out, const float* __restrict__ stats,
                     const float* __restrict__ gamma, const float* __restrict__ beta) {
    const int blk = blockIdx.x;            // b*256 + o
    const int b = blk >> 8, o = blk & 255;
    const int gI = b * GROUPS_ + (o >> 4);
    const float n = 65536.f;               // (C/G)*H*W
    const float mean = stats[gI] / n;
    const float var  = stats[128 + gI] / n - mean * mean;
    const float inv  = rsqrtf(fmaxf(var, 0.f) + EPS_);
    const float scale = inv * gamma[o];
    const float shift = beta[o] - mean * scale;
    f32x4* p = (f32x4*)(out + ((size_t)blk << 12));
    const int t = threadIdx.x;
#pragma unroll
    for (int i = 0; i < 4; ++i) {
        f32x4 v = p[t + i * 256];
        p[t + i * 256] = v * scale + shift;
    }
}

extern "C" void kernel_launch(void* const* d_in, const int* in_sizes, int n_in,
                              void* d_out, int out_size, void* d_ws, size_t ws_size,
                              hipStream_t stream) {
    const float* x     = (const float*)d_in[0];
    const float* offp  = (const float*)d_in[1];
    const float* mskp  = (const float*)d_in[2];
    const float* w     = (const float*)d_in[3];
    const float* gamma = (const float*)d_in[4];
    const float* beta  = (const float*)d_in[5];
    float* outp = (float*)d_out;

    u16*   xt    = (u16*)d_ws;
    u16*   wimg  = (u16*)((char*)d_ws + WIMG_OFF);
    float* stats = (float*)((char*)d_ws + STATS_OFF);

    k_prep<<<dim3(2048 + 288 + 1), dim3(256), 0, stream>>>(x, xt, w, wimg, stats);
    k_dcn<<<dim3(256), dim3(1024), 0, stream>>>(xt, wimg, offp, mskp, outp, stats);
    k_gn<<<dim3(2048), dim3(256), 0, stream>>>(outp, stats, gamma, beta);
}